// Round 8
// baseline (114.380 us; speedup 1.0000x reference)
//
#include <hip/hip_runtime.h>
#include <cmath>

// DotMaskLayer: B=16384, D=256, H=64, M=128.
// keep(j) = (j < K) | (128 <= j < 128+K)  [j=256 bias iff K>128; K<=128 in data]
// out[b,h] = tanh( sum_j keep(j)*Y[b,j]*W[b,j,h] ),  W = AUX.reshape(B,257,64)
// Y[b,j] = X[b,j] for j<256, Y[b,256] = 1.
//
// R8: R7 (256t block per b, 4-wave split-K, 2x 4-row chunks per wave-iter)
// + raw s_barrier per iteration to keep the 4 waves LOCKSTEP. Without it the
// waves drift and the block's in-flight read window fragments; with it, each
// block-iteration issues two contiguous 8KB request groups (rows 32u..32u+31
// and the +128 mirror). Trip count U = ceil(ceil(k/4)/8) is block-uniform
// (computed from k) -> no barrier divergence. Raw s_barrier only aligns
// execution; no vmcnt drain (LDS is touched only in the epilogue).

#define D_DIM 256
#define H_DIM 64
#define ROWS 257
#define ROWSTRIDE (ROWS * H_DIM)   // 16448 floats per batch row of AUX

__global__ __launch_bounds__(256, 8)
void dotmask_kernel(const float* __restrict__ X,
                    const float* __restrict__ AUX,
                    const int* __restrict__ K,
                    float* __restrict__ out)
{
    const int b    = blockIdx.x;
    const int tid  = threadIdx.x;
    const int lane = tid & 63;
    const int w    = tid >> 6;          // wave id 0..3 (all share row b)
    const int jo   = lane >> 4;         // row offset within 4-row chunk
    const int h4   = (lane & 15) * 4;   // this lane's 4 consecutive h's

    const int k = K[b];
    const float* __restrict__ Wb  = AUX + (size_t)b * ROWSTRIDE;
    const float* __restrict__ WbH = Wb + h4;
    const float* __restrict__ Xb  = X   + (size_t)b * D_DIM;

    float ax = 0.f, ay = 0.f, az = 0.f, aw = 0.f;

    const int C = (k + 3) >> 2;   // total 4-row chunks per side
    const int U = (C + 7) >> 3;   // block-iterations: 8 chunks (32 rows)/iter

    for (int u = 0; u < U; ++u) {
        __builtin_amdgcn_s_barrier();       // align the 4 waves (uniform U)

        const int cA = 8 * u + w;           // wave w's first chunk this iter
        const int cB = cA + 4;              // second chunk

        if (cB < C) {
            // common case: both chunks valid. Issue all 8 loads, then FMAs.
            const int ja   = 4 * cA + jo;               // <= 4C-1 <= k+3 <= 131
            const int jb   = 4 * cB + jo;
            const int ja2  = (ja + 128 > 256) ? 256 : (ja + 128);
            const int jb2  = (jb + 128 > 256) ? 256 : (jb + 128);

            const float4 wa1 = *reinterpret_cast<const float4*>(WbH + ((size_t)ja  << 6));
            const float4 wa2 = *reinterpret_cast<const float4*>(WbH + ((size_t)ja2 << 6));
            const float4 wb1 = *reinterpret_cast<const float4*>(WbH + ((size_t)jb  << 6));
            const float4 wb2 = *reinterpret_cast<const float4*>(WbH + ((size_t)jb2 << 6));
            const float  xa1r = Xb[ja];
            const float  xa2r = Xb[(ja + 128 > 255) ? 255 : (ja + 128)];
            const float  xb1r = Xb[jb];
            const float  xb2r = Xb[(jb + 128 > 255) ? 255 : (jb + 128)];

            const float xa1 = (ja < k) ? xa1r : 0.f;
            const float xa2 = (ja < k) ? xa2r : 0.f;
            const float xb1 = (jb < k) ? xb1r : 0.f;
            const float xb2 = (jb < k) ? xb2r : 0.f;

            ax += xa1 * wa1.x; ay += xa1 * wa1.y; az += xa1 * wa1.z; aw += xa1 * wa1.w;
            ax += xa2 * wa2.x; ay += xa2 * wa2.y; az += xa2 * wa2.z; aw += xa2 * wa2.w;
            ax += xb1 * wb1.x; ay += xb1 * wb1.y; az += xb1 * wb1.z; aw += xb1 * wb1.w;
            ax += xb2 * wb2.x; ay += xb2 * wb2.y; az += xb2 * wb2.z; aw += xb2 * wb2.w;
        } else if (cA < C) {
            // tail: chunk A only
            const int ja  = 4 * cA + jo;
            const int ja2 = (ja + 128 > 256) ? 256 : (ja + 128);

            const float4 wa1 = *reinterpret_cast<const float4*>(WbH + ((size_t)ja  << 6));
            const float4 wa2 = *reinterpret_cast<const float4*>(WbH + ((size_t)ja2 << 6));
            const float  xa1r = Xb[ja];
            const float  xa2r = Xb[(ja + 128 > 255) ? 255 : (ja + 128)];

            const float xa1 = (ja < k) ? xa1r : 0.f;
            const float xa2 = (ja < k) ? xa2r : 0.f;

            ax += xa1 * wa1.x; ay += xa1 * wa1.y; az += xa1 * wa1.z; aw += xa1 * wa1.w;
            ax += xa2 * wa2.x; ay += xa2 * wa2.y; az += xa2 * wa2.z; aw += xa2 * wa2.w;
        }
    }

    // bias row j=256 (kept iff k > 128; never with this data, kept for generality)
    if (k > 128 && w == 0 && jo == 0) {
        const float4 wv = *reinterpret_cast<const float4*>(Wb + (size_t)256 * H_DIM + h4);
        ax += wv.x; ay += wv.y; az += wv.z; aw += wv.w;
    }

    // reduce across the 4 jo-groups (lanes l, l+16, l+32, l+48 share h4)
    ax += __shfl_xor(ax, 16); ay += __shfl_xor(ay, 16);
    az += __shfl_xor(az, 16); aw += __shfl_xor(aw, 16);
    ax += __shfl_xor(ax, 32); ay += __shfl_xor(ay, 32);
    az += __shfl_xor(az, 32); aw += __shfl_xor(aw, 32);

    // combine the 4 waves' partials via LDS
    __shared__ float lds[4][H_DIM];
    if (lane < 16) {
        float4 p; p.x = ax; p.y = ay; p.z = az; p.w = aw;
        *reinterpret_cast<float4*>(&lds[w][h4]) = p;
    }
    __syncthreads();

    if (tid < H_DIM) {
        const float s = lds[0][tid] + lds[1][tid] + lds[2][tid] + lds[3][tid];
        out[(size_t)b * H_DIM + tid] = tanhf(s);
    }
}

extern "C" void kernel_launch(void* const* d_in, const int* in_sizes, int n_in,
                              void* d_out, int out_size, void* d_ws, size_t ws_size,
                              hipStream_t stream)
{
    const float* X   = (const float*)d_in[0];
    const float* AUX = (const float*)d_in[1];
    const int*   K   = (const int*)d_in[2];
    float* out = (float*)d_out;

    const int B = in_sizes[2];                 // 16384
    dotmask_kernel<<<B, 256, 0, stream>>>(X, AUX, K, out);
}